// Round 1
// baseline (127.522 us; speedup 1.0000x reference)
//
#include <hip/hip_runtime.h>
#include <stdint.h>

#define NB 16
#define NC 128
#define NOC 128
#define NF 64
#define NT 256
#define NCTX 128
#define NTAPS 9
#define NFLAT 147456
#define TEMPR 30.0f

#define ICP 40          // padded ic stride in LDS (elements)
#define XCOLS 258       // 256 t + 2 halo cols
#define SX_ELEMS (3*XCOLS*ICP)     // 30960
#define SW_ELEMS (NTAPS*NOC*ICP)   // 46080

typedef float f32x4 __attribute__((ext_vector_type(4)));
typedef __bf16 bf16x8 __attribute__((ext_vector_type(8)));
typedef unsigned int u32x4 __attribute__((ext_vector_type(4)));

__device__ __forceinline__ unsigned short f2bf(float f) {
    union { float f; unsigned u; } v; v.f = f;
    unsigned r = v.u + 0x7fffu + ((v.u >> 16) & 1u);   // RNE
    return (unsigned short)(r >> 16);
}

// ---------------- kernel 1: attention (16 x softmax over 4) ----------------
__global__ void attn_kernel(const float* __restrict__ g,
                            const float* __restrict__ dk,
                            const float* __restrict__ bias,
                            float* __restrict__ att) {
    int b = threadIdx.x;
    if (b >= NB) return;
    float r0 = bias[0], r1 = bias[1], r2 = bias[2], r3 = bias[3];
    const float* gb = g + b * NCTX;
    for (int c = 0; c < NCTX; ++c) {
        float gv = gb[c];
        r0 += gv * dk[c*4+0];
        r1 += gv * dk[c*4+1];
        r2 += gv * dk[c*4+2];
        r3 += gv * dk[c*4+3];
    }
    r0 *= (1.0f/TEMPR); r1 *= (1.0f/TEMPR); r2 *= (1.0f/TEMPR); r3 *= (1.0f/TEMPR);
    float mx = fmaxf(fmaxf(r0, r1), fmaxf(r2, r3));
    float e0 = expf(r0-mx), e1 = expf(r1-mx), e2 = expf(r2-mx), e3 = expf(r3-mx);
    float s = e0+e1+e2+e3;
    att[b*4+0] = e0/s; att[b*4+1] = e1/s; att[b*4+2] = e2/s; att[b*4+3] = e3/s;
}

// ------- kernel 2: blend 4 banks -> bf16 W[b][tap][oc][ic] -------
__global__ void agg_kernel(const float* __restrict__ w,
                           const float* __restrict__ att,
                           unsigned short* __restrict__ wb) {
    int idx = blockIdx.x * 256 + threadIdx.x;   // 16*128*128 = 262144
    int ic = idx & 127;
    int oc = (idx >> 7) & 127;
    int b  = idx >> 14;
    float a0 = att[b*4+0], a1 = att[b*4+1], a2 = att[b*4+2], a3 = att[b*4+3];
    int d0 = (oc*NC + ic) * NTAPS;
    #pragma unroll
    for (int tap = 0; tap < NTAPS; ++tap) {
        float s = a0 * w[0*NFLAT + d0 + tap]
                + a1 * w[1*NFLAT + d0 + tap]
                + a2 * w[2*NFLAT + d0 + tap]
                + a3 * w[3*NFLAT + d0 + tap];
        wb[((b*NTAPS + tap)*NOC + oc)*NC + ic] = f2bf(s);
    }
}

// ------------------- kernel 3: MFMA implicit-GEMM conv -------------------
__global__ __launch_bounds__(512) void conv_kernel(
        const float* __restrict__ x,
        const unsigned short* __restrict__ wb,
        float* __restrict__ out) {
    __shared__ unsigned short sx[SX_ELEMS];   // [3][258][40] bf16 bits
    __shared__ unsigned short sw[SW_ELEMS];   // [9][128][40] bf16 bits

    // bijective XCD swizzle: each XCD gets 128 contiguous logical blocks = 2 batches
    const int p  = blockIdx.x;
    const int lg = (p & 7) * 128 + (p >> 3);
    const int b  = lg >> 6;
    const int y  = lg & 63;

    const int tid  = threadIdx.x;
    const int lane = tid & 63;
    const int wid  = tid >> 6;
    const int wpix = wid & 3;    // 64-pix quadrant
    const int woc  = wid >> 2;   // 64-oc half
    const int l15  = lane & 15;
    const int l4   = lane >> 4;

    f32x4 acc[4][4];
    #pragma unroll
    for (int m = 0; m < 4; ++m)
        #pragma unroll
        for (int n = 0; n < 4; ++n)
            acc[m][n] = (f32x4){0.f, 0.f, 0.f, 0.f};

    const float* xb = x + (b * NC) * (NF * NT);
    const unsigned short* wbb = wb + b * (NTAPS * NOC * NC);

    for (int c4 = 0; c4 < 4; ++c4) {
        const int ic0 = c4 * 32;
        __syncthreads();   // previous tap-phase reads done before overwrite

        // ---- stage X: 3 rows x 256 t x 32 ic, fp32 -> bf16, transposed to [r][c][ic]
        // item w_: qlo=w_&3, i2=(w_>>2)&15, qhi=(w_>>6)&15, r=w_>>10 ; q=qhi*4+qlo
        #pragma unroll
        for (int j = 0; j < 6; ++j) {
            int w_  = tid + j * 512;
            int qlo = w_ & 3;
            int i2  = (w_ >> 2) & 15;
            int qhi = (w_ >> 6) & 15;
            int r   = w_ >> 10;
            int q   = qhi * 4 + qlo;
            int iy  = y - 1 + r;
            f32x4 v0 = (f32x4){0.f,0.f,0.f,0.f};
            f32x4 v1 = v0;
            if ((unsigned)iy < (unsigned)NF) {
                const float* src = xb + ((ic0 + 2*i2) * NF + iy) * NT + q * 4;
                v0 = *(const f32x4*)src;
                v1 = *(const f32x4*)(src + NF * NT);
            }
            unsigned short* dst = sx + (r * XCOLS + q*4 + 1) * ICP + 2*i2;
            #pragma unroll
            for (int jj = 0; jj < 4; ++jj) {
                unsigned pk = (unsigned)f2bf(v0[jj]) | ((unsigned)f2bf(v1[jj]) << 16);
                *(unsigned*)(dst + jj * ICP) = pk;
            }
        }
        // halo columns c=0 (t=-1) and c=257 (t=256) are zero
        if (tid < 96) {
            int i2 = tid & 15;
            int rr = tid >> 4;            // 0..5
            int r  = rr % 3;
            int c  = (rr / 3) ? (XCOLS - 1) : 0;
            *(unsigned*)(sx + (r * XCOLS + c) * ICP + 2*i2) = 0u;
        }

        // ---- stage W: 9*128 rows x 32 ic, 16B copies
        #pragma unroll
        for (int j = 0; j < 9; ++j) {
            int w_  = tid + j * 512;
            int row = w_ >> 2;            // tap*128 + oc
            int q4  = w_ & 3;
            u32x4 d = *(const u32x4*)(wbb + row * NC + ic0 + q4 * 8);
            *(u32x4*)(sw + row * ICP + q4 * 8) = d;
        }
        __syncthreads();

        // ---- compute: 9 taps x 16 MFMA per wave
        const unsigned short* swp = sw + (woc * 64 + l15) * ICP + l4 * 8;
        const unsigned short* sxp = sx + (wpix * 64 + l15) * ICP + l4 * 8;
        #pragma unroll
        for (int ky = 0; ky < 3; ++ky) {
            #pragma unroll
            for (int kx = 0; kx < 3; ++kx) {
                const int tap = ky * 3 + kx;
                bf16x8 af[4], bfv[4];
                #pragma unroll
                for (int m = 0; m < 4; ++m)
                    af[m] = *(const bf16x8*)(swp + (tap * NOC + m * 16) * ICP);
                #pragma unroll
                for (int n = 0; n < 4; ++n)
                    bfv[n] = *(const bf16x8*)(sxp + (ky * XCOLS + kx + n * 16) * ICP);
                #pragma unroll
                for (int m = 0; m < 4; ++m)
                    #pragma unroll
                    for (int n = 0; n < 4; ++n)
                        acc[m][n] = __builtin_amdgcn_mfma_f32_16x16x32_bf16(
                            af[m], bfv[n], acc[m][n], 0, 0, 0);
            }
        }
    }

    // ---- epilogue: D[row=oc=(l>>4)*4+r][col=pix=l&15] -> 64B-contiguous stores
    #pragma unroll
    for (int m = 0; m < 4; ++m) {
        int ocb = woc * 64 + m * 16 + l4 * 4;
        #pragma unroll
        for (int r = 0; r < 4; ++r) {
            float* orow = out + ((b * NOC + ocb + r) * NF + y) * NT;
            #pragma unroll
            for (int n = 0; n < 4; ++n)
                orow[wpix * 64 + n * 16 + l15] = acc[m][n][r];
        }
    }
}

extern "C" void kernel_launch(void* const* d_in, const int* in_sizes, int n_in,
                              void* d_out, int out_size, void* d_ws, size_t ws_size,
                              hipStream_t stream) {
    const float* x    = (const float*)d_in[0];
    const float* g    = (const float*)d_in[1];
    const float* dk   = (const float*)d_in[2];
    const float* bias = (const float*)d_in[3];
    const float* w    = (const float*)d_in[4];
    float* out = (float*)d_out;

    float* att = (float*)d_ws;                                  // 64 floats
    unsigned short* wb = (unsigned short*)((char*)d_ws + 256);  // 16*9*128*128 bf16

    attn_kernel<<<dim3(1), dim3(64), 0, stream>>>(g, dk, bias, att);
    agg_kernel<<<dim3(1024), dim3(256), 0, stream>>>(w, att, wb);
    conv_kernel<<<dim3(1024), dim3(512), 0, stream>>>(x, wb, out);
}